// Round 7
// baseline (901.123 us; speedup 1.0000x reference)
//
#include <hip/hip_runtime.h>

#define NN 100000
#define EE 1000000
#define ET (EE + NN)
#define HC 128
#define NB 391           // ceil(NN/256)

// pack two floats to bf16x2 (RNE), head0 in low 16, head1 in high 16
__device__ __forceinline__ unsigned bfpack(float a, float b) {
    unsigned ua = __float_as_uint(a), ub = __float_as_uint(b);
    ua += 0x7fff + ((ua >> 16) & 1);
    ub += 0x7fff + ((ub >> 16) & 1);
    return (ua >> 16) | (ub & 0xffff0000u);
}

// ---- K1: h = x @ W (+ fused attention dots); h stored bf16-packed ----
__global__ __launch_bounds__(256) void k_gemm(
    const float* __restrict__ x, const float* __restrict__ W,
    const float* __restrict__ atts, const float* __restrict__ attd,
    unsigned* __restrict__ hB, float* __restrict__ asrc, float* __restrict__ adst)
{
    __shared__ float Wl[HC * HC];   // 64 KB
    for (int i = threadIdx.x * 4; i < HC * HC; i += 256 * 4)
        *(float4*)&Wl[i] = *(const float4*)&W[i];
    __syncthreads();

    const int wv = threadIdx.x >> 6, lane = threadIdx.x & 63;
    const float as0 = atts[lane], as1 = atts[64 + lane];
    const float ad0 = attd[lane], ad1 = attd[64 + lane];

    for (int row = blockIdx.x * 4 + wv; row < NN; row += gridDim.x * 4) {
        const float* xr = x + (size_t)row * HC;
        float acc0 = 0.f, acc1 = 0.f;
        #pragma unroll 4
        for (int k4 = 0; k4 < HC / 4; ++k4) {
            const float4 xv = *(const float4*)(xr + k4 * 4);
            const int b = k4 * 4 * HC + lane;
            acc0 = fmaf(xv.x, Wl[b],            acc0);
            acc1 = fmaf(xv.x, Wl[b + 64],       acc1);
            acc0 = fmaf(xv.y, Wl[b + HC],       acc0);
            acc1 = fmaf(xv.y, Wl[b + HC + 64],  acc1);
            acc0 = fmaf(xv.z, Wl[b + 2*HC],     acc0);
            acc1 = fmaf(xv.z, Wl[b + 2*HC + 64],acc1);
            acc0 = fmaf(xv.w, Wl[b + 3*HC],     acc0);
            acc1 = fmaf(xv.w, Wl[b + 3*HC + 64],acc1);
        }
        hB[(size_t)row * 64 + lane] = bfpack(acc0, acc1);

        float p0 = acc0 * as0, p1 = acc1 * as1;
        float q0 = acc0 * ad0, q1 = acc1 * ad1;
        for (int m = 32; m; m >>= 1) {
            p0 += __shfl_xor(p0, m); p1 += __shfl_xor(p1, m);
            q0 += __shfl_xor(q0, m); q1 += __shfl_xor(q1, m);
        }
        if (!lane) {
            asrc[row * 2] = p0; asrc[row * 2 + 1] = p1;
            adst[row * 2] = q0; adst[row * 2 + 1] = q1;
        }
    }
}

__device__ __forceinline__ void edge_sd(const int* __restrict__ ei, int t, int& s, int& d) {
    if (t < EE) { s = ei[t]; d = ei[EE + t]; }
    else        { s = t - EE; d = t - EE; }           // self-loops appended
}

// ---- CSR build ----
__global__ __launch_bounds__(256) void k_hist(const int* __restrict__ ei,
                                              int* __restrict__ hist)
{
    int t = blockIdx.x * 256 + threadIdx.x;
    if (t >= ET) return;
    int d = (t < EE) ? ei[EE + t] : (t - EE);
    atomicAdd(&hist[d], 1);
}

__global__ __launch_bounds__(256) void k_scan1(const int* __restrict__ hist,
                                               int* __restrict__ part)
{
    __shared__ int ls[256];
    int i = blockIdx.x * 256 + threadIdx.x;
    ls[threadIdx.x] = (i < NN) ? hist[i] : 0;
    __syncthreads();
    for (int off = 128; off; off >>= 1) {
        if (threadIdx.x < off) ls[threadIdx.x] += ls[threadIdx.x + off];
        __syncthreads();
    }
    if (!threadIdx.x) part[blockIdx.x] = ls[0];
}

__global__ __launch_bounds__(512) void k_scan2(int* __restrict__ part)
{
    __shared__ int ls[512];
    int tid = threadIdx.x;
    int v = (tid < NB) ? part[tid] : 0;
    ls[tid] = v;
    __syncthreads();
    for (int off = 1; off < 512; off <<= 1) {
        int t = (tid >= off) ? ls[tid - off] : 0;
        __syncthreads();
        ls[tid] += t;
        __syncthreads();
    }
    if (tid < NB) part[tid] = ls[tid] - v;   // exclusive block offsets
}

__global__ __launch_bounds__(256) void k_scan3(const int* __restrict__ hist,
                                               const int* __restrict__ part,
                                               int* __restrict__ row_ptr)
{
    __shared__ int ls[256];
    int i = blockIdx.x * 256 + threadIdx.x;
    int v = (i < NN) ? hist[i] : 0;
    ls[threadIdx.x] = v;
    __syncthreads();
    for (int off = 1; off < 256; off <<= 1) {
        int t = (threadIdx.x >= off) ? ls[threadIdx.x - off] : 0;
        __syncthreads();
        ls[threadIdx.x] += t;
        __syncthreads();
    }
    if (i < NN) row_ptr[i] = part[blockIdx.x] + ls[threadIdx.x] - v;  // exclusive
    if (i == 0) row_ptr[NN] = ET;
}

// bucket edges by dst; also compute p = exp(leaky_relu(logit)) in CSR order
__global__ __launch_bounds__(256) void k_bucket(
    const int* __restrict__ ei, const float* __restrict__ asrc,
    const float* __restrict__ adst, const int* __restrict__ row_ptr,
    int* __restrict__ cursor, int* __restrict__ csr_src, float2* __restrict__ pexp)
{
    int t = blockIdx.x * 256 + threadIdx.x;
    if (t >= ET) return;
    int s, d; edge_sd(ei, t, s, d);
    float2 av = *(const float2*)&asrc[s * 2];
    float2 dv = *(const float2*)&adst[d * 2];
    float e0 = av.x + dv.x; e0 = e0 > 0.f ? e0 : 0.2f * e0;
    float e1 = av.y + dv.y; e1 = e1 > 0.f ? e1 : 0.2f * e1;
    int pos = row_ptr[d] + atomicAdd(&cursor[d], 1);
    csr_src[pos] = s;
    pexp[pos] = make_float2(__expf(e0), __expf(e1));
}

// 8 independent gathers issued + drained in ONE asm block: nothing (spill,
// copy, compiler waitcnt) can land between issue and drain. saddr form:
// 32-bit byte offsets + SGPR base (hB spans 25.6MB < 2^31).
__device__ __forceinline__ void gather8(const unsigned* base, const unsigned* off,
                                        unsigned* w) {
    asm volatile(
        "global_load_dword %0, %8,  %16\n\t"
        "global_load_dword %1, %9,  %16\n\t"
        "global_load_dword %2, %10, %16\n\t"
        "global_load_dword %3, %11, %16\n\t"
        "global_load_dword %4, %12, %16\n\t"
        "global_load_dword %5, %13, %16\n\t"
        "global_load_dword %6, %14, %16\n\t"
        "global_load_dword %7, %15, %16\n\t"
        "s_waitcnt vmcnt(0)"
        : "=&v"(w[0]), "=&v"(w[1]), "=&v"(w[2]), "=&v"(w[3]),
          "=&v"(w[4]), "=&v"(w[5]), "=&v"(w[6]), "=&v"(w[7])
        : "v"(off[0]), "v"(off[1]), "v"(off[2]), "v"(off[3]),
          "v"(off[4]), "v"(off[5]), "v"(off[6]), "v"(off[7]),
          "s"(base)
        : "memory");
}

// ---- K-agg v6: 8-wide in-flight gathers via single asm block ----
__global__ __launch_bounds__(256) void k_agg(
    const int* __restrict__ row_ptr, const int* __restrict__ csr_src,
    const float2* __restrict__ pexp, const unsigned* __restrict__ hB,
    const float* __restrict__ bias,
    float* __restrict__ out, float* __restrict__ gsum, float* __restrict__ gsq)
{
    __shared__ float lsum[HC], lsq[HC];
    __shared__ int    lidx[4][64];
    __shared__ float2 lp[4][64];
    const int tid = threadIdx.x;
    if (tid < HC) { lsum[tid] = 0.f; lsq[tid] = 0.f; }
    __syncthreads();

    const int wv = tid >> 6, lane = tid & 63;
    const int node = blockIdx.x * 4 + wv;           // grid = NN/4 exactly
    const int beg = row_ptr[node], end = row_ptr[node + 1];  // end > beg

    float s0 = 0.f, s1 = 0.f;        // per-lane partial sum of p
    float acc0 = 0.f, acc1 = 0.f;    // unnormalized aggregate

    for (int base = beg; base < end; base += 64) {
        const int cnt = min(64, end - base);   // >= 1
        if (lane < cnt) {
            float2 pv = pexp[base + lane];
            lidx[wv][lane] = csr_src[base + lane];
            lp[wv][lane] = pv;
            s0 += pv.x; s1 += pv.y;
        }
        for (int j0 = 0; j0 < cnt; j0 += 8) {
            unsigned off[8], w[8];
            float pwx[8], pwy[8];
            #pragma unroll
            for (int u = 0; u < 8; ++u) {
                int j  = j0 + u;
                int jc = j < cnt ? j : cnt - 1;     // clamp (wave-uniform select)
                int s  = lidx[wv][jc];
                float2 pv = lp[wv][jc];
                pwx[u] = j < cnt ? pv.x : 0.f;      // zero pad weight
                pwy[u] = j < cnt ? pv.y : 0.f;
                off[u] = ((unsigned)s * 64u + (unsigned)lane) * 4u;  // byte offset
            }
            gather8(hB, off, w);
            #pragma unroll
            for (int u = 0; u < 8; ++u) {
                acc0 = fmaf(pwx[u], __uint_as_float(w[u] << 16),         acc0);
                acc1 = fmaf(pwy[u], __uint_as_float(w[u] & 0xffff0000u), acc1);
            }
        }
    }

    for (int off = 32; off; off >>= 1) {
        s0 += __shfl_xor(s0, off);
        s1 += __shfl_xor(s1, off);
    }

    float v0 = acc0 / s0 + bias[lane];      v0 = v0 > 0.f ? v0 : 0.f;
    float v1 = acc1 / s1 + bias[64 + lane]; v1 = v1 > 0.f ? v1 : 0.f;
    out[(size_t)node * HC + lane]      = v0;
    out[(size_t)node * HC + 64 + lane] = v1;

    atomicAdd(&lsum[lane], v0);      atomicAdd(&lsq[lane], v0 * v0);
    atomicAdd(&lsum[64 + lane], v1); atomicAdd(&lsq[64 + lane], v1 * v1);
    __syncthreads();
    if (tid < HC) {
        atomicAdd(&gsum[tid], lsum[tid]);
        atomicAdd(&gsq[tid],  lsq[tid]);
    }
}

// ---- BN scale/shift ----
__global__ void k_bnparam(const float* __restrict__ gsum, const float* __restrict__ gsq,
                          const float* __restrict__ gamma, const float* __restrict__ beta,
                          float* __restrict__ scsh)
{
    int c = threadIdx.x;  // 128
    float mean = gsum[c] * (1.f / NN);
    float var  = gsq[c] * (1.f / NN) - mean * mean;
    float sc   = gamma[c] * rsqrtf(var + 1e-5f);
    scsh[c]       = sc;
    scsh[128 + c] = beta[c] - mean * sc;
}

// ---- affine apply in place (float4) ----
__global__ __launch_bounds__(256) void k_apply(float* __restrict__ out,
                                               const float* __restrict__ scsh)
{
    size_t i = (size_t)blockIdx.x * 256 + threadIdx.x;
    if (i * 4 >= (size_t)NN * HC) return;
    float4 v = ((float4*)out)[i];
    int c = (int)((i * 4) & (HC - 1));
    v.x = v.x * scsh[c]     + scsh[128 + c];
    v.y = v.y * scsh[c + 1] + scsh[128 + c + 1];
    v.z = v.z * scsh[c + 2] + scsh[128 + c + 2];
    v.w = v.w * scsh[c + 3] + scsh[128 + c + 3];
    ((float4*)out)[i] = v;
}

extern "C" void kernel_launch(void* const* d_in, const int* in_sizes, int n_in,
                              void* d_out, int out_size, void* d_ws, size_t ws_size,
                              hipStream_t stream) {
    const float* x     = (const float*)d_in[0];
    const int*   ei    = (const int*)  d_in[1];
    const float* W     = (const float*)d_in[2];
    const float* atts  = (const float*)d_in[3];
    const float* attd  = (const float*)d_in[4];
    const float* bias  = (const float*)d_in[5];
    const float* gamma = (const float*)d_in[6];
    const float* beta  = (const float*)d_in[7];
    float* out = (float*)d_out;
    float* ws  = (float*)d_ws;

    // ws layout (float-sized slots), ~41.6 MB total
    unsigned* hB     = (unsigned*)ws;             //  6,400,000
    float*    asrc   = ws + 6400000;              //    200,000
    float*    adst   = ws + 6600000;              //    200,000
    int*      hist   = (int*)(ws + 6800000);      //    100,000  \  zeroed
    int*      cursor = (int*)(ws + 6900000);      //    100,000   } region
    float*    gsum   = ws + 7000000;              //        128   } (200,256)
    float*    gsq    = ws + 7000128;              //        128  /
    float*    scsh   = ws + 7000256;              //        256
    int*      row_ptr= (int*)(ws + 7000512);      //    100,001
    int*      part   = (int*)(ws + 7100513);      //        512
    int*      csr_src= (int*)(ws + 7101025);      //  1,100,000
    float2*   pexp   = (float2*)(ws + 8201026);   //  2,200,000 floats (8B aligned)

    hipMemsetAsync(hist, 0, (size_t)200256 * sizeof(int), stream);

    k_gemm  <<<2048, 256, 0, stream>>>(x, W, atts, attd, hB, asrc, adst);
    k_hist  <<<(ET + 255) / 256, 256, 0, stream>>>(ei, hist);
    k_scan1 <<<NB, 256, 0, stream>>>(hist, part);
    k_scan2 <<<1, 512, 0, stream>>>(part);
    k_scan3 <<<NB, 256, 0, stream>>>(hist, part, row_ptr);
    k_bucket<<<(ET + 255) / 256, 256, 0, stream>>>(ei, asrc, adst, row_ptr,
                                                   cursor, csr_src, pexp);
    k_agg   <<<NN / 4, 256, 0, stream>>>(row_ptr, csr_src, pexp, hB, bias,
                                         out, gsum, gsq);
    k_bnparam<<<1, 128, 0, stream>>>(gsum, gsq, gamma, beta, scsh);
    k_apply <<<(NN * HC / 4 + 255) / 256, 256, 0, stream>>>(out, scsh);
}

// Round 8
// 452.670 us; speedup vs baseline: 1.9907x; 1.9907x over previous
//
#include <hip/hip_runtime.h>

#define NN 100000
#define EE 1000000
#define ET (EE + NN)
#define HC 128
#define NB 391           // ceil(NN/256)
#define AGG_BLOCKS 2048  // persistent blocks for k_agg
#define NGRP (NN / 4)    // 25000 node groups of 4

// pack two floats to bf16x2 (RNE), head0 in low 16, head1 in high 16
__device__ __forceinline__ unsigned bfpack(float a, float b) {
    unsigned ua = __float_as_uint(a), ub = __float_as_uint(b);
    ua += 0x7fff + ((ua >> 16) & 1);
    ub += 0x7fff + ((ub >> 16) & 1);
    return (ua >> 16) | (ub & 0xffff0000u);
}

// ---- K1: h = x @ W (+ fused attention dots); h stored bf16-packed ----
__global__ __launch_bounds__(256) void k_gemm(
    const float* __restrict__ x, const float* __restrict__ W,
    const float* __restrict__ atts, const float* __restrict__ attd,
    unsigned* __restrict__ hB, float* __restrict__ asrc, float* __restrict__ adst)
{
    __shared__ float Wl[HC * HC];   // 64 KB
    for (int i = threadIdx.x * 4; i < HC * HC; i += 256 * 4)
        *(float4*)&Wl[i] = *(const float4*)&W[i];
    __syncthreads();

    const int wv = threadIdx.x >> 6, lane = threadIdx.x & 63;
    const float as0 = atts[lane], as1 = atts[64 + lane];
    const float ad0 = attd[lane], ad1 = attd[64 + lane];

    for (int row = blockIdx.x * 4 + wv; row < NN; row += gridDim.x * 4) {
        const float* xr = x + (size_t)row * HC;
        float acc0 = 0.f, acc1 = 0.f;
        #pragma unroll 4
        for (int k4 = 0; k4 < HC / 4; ++k4) {
            const float4 xv = *(const float4*)(xr + k4 * 4);
            const int b = k4 * 4 * HC + lane;
            acc0 = fmaf(xv.x, Wl[b],            acc0);
            acc1 = fmaf(xv.x, Wl[b + 64],       acc1);
            acc0 = fmaf(xv.y, Wl[b + HC],       acc0);
            acc1 = fmaf(xv.y, Wl[b + HC + 64],  acc1);
            acc0 = fmaf(xv.z, Wl[b + 2*HC],     acc0);
            acc1 = fmaf(xv.z, Wl[b + 2*HC + 64],acc1);
            acc0 = fmaf(xv.w, Wl[b + 3*HC],     acc0);
            acc1 = fmaf(xv.w, Wl[b + 3*HC + 64],acc1);
        }
        hB[(size_t)row * 64 + lane] = bfpack(acc0, acc1);

        float p0 = acc0 * as0, p1 = acc1 * as1;
        float q0 = acc0 * ad0, q1 = acc1 * ad1;
        for (int m = 32; m; m >>= 1) {
            p0 += __shfl_xor(p0, m); p1 += __shfl_xor(p1, m);
            q0 += __shfl_xor(q0, m); q1 += __shfl_xor(q1, m);
        }
        if (!lane) {
            asrc[row * 2] = p0; asrc[row * 2 + 1] = p1;
            adst[row * 2] = q0; adst[row * 2 + 1] = q1;
        }
    }
}

__device__ __forceinline__ void edge_sd(const int* __restrict__ ei, int t, int& s, int& d) {
    if (t < EE) { s = ei[t]; d = ei[EE + t]; }
    else        { s = t - EE; d = t - EE; }           // self-loops appended
}

// ---- CSR build ----
__global__ __launch_bounds__(256) void k_hist(const int* __restrict__ ei,
                                              int* __restrict__ hist)
{
    int t = blockIdx.x * 256 + threadIdx.x;
    if (t >= ET) return;
    int d = (t < EE) ? ei[EE + t] : (t - EE);
    atomicAdd(&hist[d], 1);
}

__global__ __launch_bounds__(256) void k_scan1(const int* __restrict__ hist,
                                               int* __restrict__ part)
{
    __shared__ int ls[256];
    int i = blockIdx.x * 256 + threadIdx.x;
    ls[threadIdx.x] = (i < NN) ? hist[i] : 0;
    __syncthreads();
    for (int off = 128; off; off >>= 1) {
        if (threadIdx.x < off) ls[threadIdx.x] += ls[threadIdx.x + off];
        __syncthreads();
    }
    if (!threadIdx.x) part[blockIdx.x] = ls[0];
}

__global__ __launch_bounds__(512) void k_scan2(int* __restrict__ part)
{
    __shared__ int ls[512];
    int tid = threadIdx.x;
    int v = (tid < NB) ? part[tid] : 0;
    ls[tid] = v;
    __syncthreads();
    for (int off = 1; off < 512; off <<= 1) {
        int t = (tid >= off) ? ls[tid - off] : 0;
        __syncthreads();
        ls[tid] += t;
        __syncthreads();
    }
    if (tid < NB) part[tid] = ls[tid] - v;   // exclusive block offsets
}

__global__ __launch_bounds__(256) void k_scan3(const int* __restrict__ hist,
                                               const int* __restrict__ part,
                                               int* __restrict__ row_ptr)
{
    __shared__ int ls[256];
    int i = blockIdx.x * 256 + threadIdx.x;
    int v = (i < NN) ? hist[i] : 0;
    ls[threadIdx.x] = v;
    __syncthreads();
    for (int off = 1; off < 256; off <<= 1) {
        int t = (threadIdx.x >= off) ? ls[threadIdx.x - off] : 0;
        __syncthreads();
        ls[threadIdx.x] += t;
        __syncthreads();
    }
    if (i < NN) row_ptr[i] = part[blockIdx.x] + ls[threadIdx.x] - v;  // exclusive
    if (i == 0) row_ptr[NN] = ET;
}

// bucket edges by dst; also compute p = exp(leaky_relu(logit)) in CSR order
__global__ __launch_bounds__(256) void k_bucket(
    const int* __restrict__ ei, const float* __restrict__ asrc,
    const float* __restrict__ adst, const int* __restrict__ row_ptr,
    int* __restrict__ cursor, int* __restrict__ csr_src, float2* __restrict__ pexp)
{
    int t = blockIdx.x * 256 + threadIdx.x;
    if (t >= ET) return;
    int s, d; edge_sd(ei, t, s, d);
    float2 av = *(const float2*)&asrc[s * 2];
    float2 dv = *(const float2*)&adst[d * 2];
    float e0 = av.x + dv.x; e0 = e0 > 0.f ? e0 : 0.2f * e0;
    float e1 = av.y + dv.y; e1 = e1 > 0.f ? e1 : 0.2f * e1;
    int pos = row_ptr[d] + atomicAdd(&cursor[d], 1);
    csr_src[pos] = s;
    pexp[pos] = make_float2(__expf(e0), __expf(e1));
}

// 8 independent gathers issued + drained in ONE asm block (sound: nothing can
// land between issue and drain). saddr form: 32-bit voffset + SGPR base.
__device__ __forceinline__ void gather8(const unsigned* base, const unsigned* off,
                                        unsigned* w) {
    asm volatile(
        "global_load_dword %0, %8,  %16\n\t"
        "global_load_dword %1, %9,  %16\n\t"
        "global_load_dword %2, %10, %16\n\t"
        "global_load_dword %3, %11, %16\n\t"
        "global_load_dword %4, %12, %16\n\t"
        "global_load_dword %5, %13, %16\n\t"
        "global_load_dword %6, %14, %16\n\t"
        "global_load_dword %7, %15, %16\n\t"
        "s_waitcnt vmcnt(0)"
        : "=&v"(w[0]), "=&v"(w[1]), "=&v"(w[2]), "=&v"(w[3]),
          "=&v"(w[4]), "=&v"(w[5]), "=&v"(w[6]), "=&v"(w[7])
        : "v"(off[0]), "v"(off[1]), "v"(off[2]), "v"(off[3]),
          "v"(off[4]), "v"(off[5]), "v"(off[6]), "v"(off[7]),
          "s"(base)
        : "memory");
}

// ---- K-agg v7: persistent blocks, BN partials written non-atomically ----
__global__ __launch_bounds__(256) void k_agg(
    const int* __restrict__ row_ptr, const int* __restrict__ csr_src,
    const float2* __restrict__ pexp, const unsigned* __restrict__ hB,
    const float* __restrict__ bias,
    float* __restrict__ out, float* __restrict__ bpart)
{
    __shared__ float lsum[HC], lsq[HC];
    __shared__ int    lidx[4][64];
    __shared__ float2 lp[4][64];
    const int tid = threadIdx.x;
    if (tid < HC) { lsum[tid] = 0.f; lsq[tid] = 0.f; }
    __syncthreads();

    const int wv = tid >> 6, lane = tid & 63;
    const float b0c = bias[lane], b1c = bias[64 + lane];

    for (int g = blockIdx.x; g < NGRP; g += AGG_BLOCKS) {
        const int node = g * 4 + wv;
        const int beg = row_ptr[node], end = row_ptr[node + 1];  // end > beg

        float s0 = 0.f, s1 = 0.f;
        float acc0 = 0.f, acc1 = 0.f;

        for (int base = beg; base < end; base += 64) {
            const int cnt = min(64, end - base);   // >= 1
            if (lane < cnt) {
                float2 pv = pexp[base + lane];
                lidx[wv][lane] = csr_src[base + lane];
                lp[wv][lane] = pv;
                s0 += pv.x; s1 += pv.y;
            }
            for (int j0 = 0; j0 < cnt; j0 += 8) {
                unsigned off[8], w[8];
                float pwx[8], pwy[8];
                #pragma unroll
                for (int u = 0; u < 8; ++u) {
                    int j  = j0 + u;
                    int jc = j < cnt ? j : cnt - 1;     // clamp (wave-uniform)
                    int s  = lidx[wv][jc];
                    float2 pv = lp[wv][jc];
                    pwx[u] = j < cnt ? pv.x : 0.f;      // zero pad weight
                    pwy[u] = j < cnt ? pv.y : 0.f;
                    off[u] = ((unsigned)s * 64u + (unsigned)lane) * 4u;
                }
                gather8(hB, off, w);
                #pragma unroll
                for (int u = 0; u < 8; ++u) {
                    acc0 = fmaf(pwx[u], __uint_as_float(w[u] << 16),         acc0);
                    acc1 = fmaf(pwy[u], __uint_as_float(w[u] & 0xffff0000u), acc1);
                }
            }
        }

        for (int off = 32; off; off >>= 1) {
            s0 += __shfl_xor(s0, off);
            s1 += __shfl_xor(s1, off);
        }

        float v0 = acc0 / s0 + b0c;  v0 = v0 > 0.f ? v0 : 0.f;
        float v1 = acc1 / s1 + b1c;  v1 = v1 > 0.f ? v1 : 0.f;
        out[(size_t)node * HC + lane]      = v0;
        out[(size_t)node * HC + 64 + lane] = v1;

        atomicAdd(&lsum[lane], v0);      atomicAdd(&lsq[lane], v0 * v0);
        atomicAdd(&lsum[64 + lane], v1); atomicAdd(&lsq[64 + lane], v1 * v1);
    }

    __syncthreads();
    // one coalesced non-atomic write of this block's 256 partials
    bpart[(size_t)blockIdx.x * 256 + tid] = tid < HC ? lsum[tid] : lsq[tid - HC];
}

// ---- reduce bpart[2048][256] -> p2[16][256] (atomic-free) ----
__global__ __launch_bounds__(256) void k_red(const float* __restrict__ bpart,
                                             float* __restrict__ p2)
{
    const int tid = threadIdx.x;
    float acc = 0.f;
    const int r0 = blockIdx.x * (AGG_BLOCKS / 16);
    #pragma unroll 4
    for (int r = 0; r < AGG_BLOCKS / 16; ++r)
        acc += bpart[(size_t)(r0 + r) * 256 + tid];
    p2[blockIdx.x * 256 + tid] = acc;
}

// ---- BN scale/shift from p2[16][256] ----
__global__ void k_bnparam(const float* __restrict__ p2,
                          const float* __restrict__ gamma, const float* __restrict__ beta,
                          float* __restrict__ scsh)
{
    int c = threadIdx.x;  // 128
    float sum = 0.f, sq = 0.f;
    #pragma unroll
    for (int i = 0; i < 16; ++i) {
        sum += p2[i * 256 + c];
        sq  += p2[i * 256 + c + 128];
    }
    float mean = sum * (1.f / NN);
    float var  = sq * (1.f / NN) - mean * mean;
    float sc   = gamma[c] * rsqrtf(var + 1e-5f);
    scsh[c]       = sc;
    scsh[128 + c] = beta[c] - mean * sc;
}

// ---- affine apply in place (float4) ----
__global__ __launch_bounds__(256) void k_apply(float* __restrict__ out,
                                               const float* __restrict__ scsh)
{
    size_t i = (size_t)blockIdx.x * 256 + threadIdx.x;
    if (i * 4 >= (size_t)NN * HC) return;
    float4 v = ((float4*)out)[i];
    int c = (int)((i * 4) & (HC - 1));
    v.x = v.x * scsh[c]     + scsh[128 + c];
    v.y = v.y * scsh[c + 1] + scsh[128 + c + 1];
    v.z = v.z * scsh[c + 2] + scsh[128 + c + 2];
    v.w = v.w * scsh[c + 3] + scsh[128 + c + 3];
    ((float4*)out)[i] = v;
}

extern "C" void kernel_launch(void* const* d_in, const int* in_sizes, int n_in,
                              void* d_out, int out_size, void* d_ws, size_t ws_size,
                              hipStream_t stream) {
    const float* x     = (const float*)d_in[0];
    const int*   ei    = (const int*)  d_in[1];
    const float* W     = (const float*)d_in[2];
    const float* atts  = (const float*)d_in[3];
    const float* attd  = (const float*)d_in[4];
    const float* bias  = (const float*)d_in[5];
    const float* gamma = (const float*)d_in[6];
    const float* beta  = (const float*)d_in[7];
    float* out = (float*)d_out;
    float* ws  = (float*)d_ws;

    // ws layout (float-sized slots), ~43.8 MB total
    unsigned* hB     = (unsigned*)ws;             //  6,400,000
    float*    asrc   = ws + 6400000;              //    200,000
    float*    adst   = ws + 6600000;              //    200,000
    int*      hist   = (int*)(ws + 6800000);      //    100,000  \  zeroed
    int*      cursor = (int*)(ws + 6900000);      //    100,000   } region
    float*    scsh   = ws + 7000256;              //        256
    int*      row_ptr= (int*)(ws + 7000512);      //    100,001
    int*      part   = (int*)(ws + 7100513);      //        512
    int*      csr_src= (int*)(ws + 7101025);      //  1,100,000
    float2*   pexp   = (float2*)(ws + 8201026);   //  2,200,000 floats
    float*    bpart  = ws + 10401026;             //    524,288 (2048*256)
    float*    p2     = ws + 10925314;             //      4,096 (16*256)

    hipMemsetAsync(hist, 0, (size_t)200000 * sizeof(int), stream);

    k_gemm  <<<2048, 256, 0, stream>>>(x, W, atts, attd, hB, asrc, adst);
    k_hist  <<<(ET + 255) / 256, 256, 0, stream>>>(ei, hist);
    k_scan1 <<<NB, 256, 0, stream>>>(hist, part);
    k_scan2 <<<1, 512, 0, stream>>>(part);
    k_scan3 <<<NB, 256, 0, stream>>>(hist, part, row_ptr);
    k_bucket<<<(ET + 255) / 256, 256, 0, stream>>>(ei, asrc, adst, row_ptr,
                                                   cursor, csr_src, pexp);
    k_agg   <<<AGG_BLOCKS, 256, 0, stream>>>(row_ptr, csr_src, pexp, hB, bias,
                                             out, bpart);
    k_red   <<<16, 256, 0, stream>>>(bpart, p2);
    k_bnparam<<<1, 128, 0, stream>>>(p2, gamma, beta, scsh);
    k_apply <<<(NN * HC / 4 + 255) / 256, 256, 0, stream>>>(out, scsh);
}

// Round 9
// 321.178 us; speedup vs baseline: 2.8057x; 1.4094x over previous
//
#include <hip/hip_runtime.h>

#define NN 100000
#define EE 1000000
#define ET (EE + NN)
#define HC 128
#define NB 391           // ceil(NN/256)
#define AGG_BLOCKS 2048  // persistent blocks for k_agg
#define NGRP (NN / 4)    // 25000 node groups of 4
#define NTILE 6250       // NN/16 row-tiles

typedef __attribute__((ext_vector_type(8))) short short8;
typedef __attribute__((ext_vector_type(4))) float f32x4;

// pack two floats to bf16x2 (RNE), first in low 16, second in high 16
__device__ __forceinline__ unsigned bfpack(float a, float b) {
    unsigned ua = __float_as_uint(a), ub = __float_as_uint(b);
    ua += 0x7fff + ((ua >> 16) & 1);
    ub += 0x7fff + ((ub >> 16) & 1);
    return (ua >> 16) | (ub & 0xffff0000u);
}

// ---- K0: pack W into MFMA B-fragment layout (bf16), 32KB in global ----
// slot (ks, nt, lane): lane l holds W[ks*32+(l>>4)*8 + j][nt*16+(l&15)], j=0..7
__global__ __launch_bounds__(64) void k_wprep(const float* __restrict__ W,
                                              uint4* __restrict__ wf)
{
    const int bid = blockIdx.x;           // ks*8 + nt
    const int ks = bid >> 3, nt = bid & 7;
    const int l = threadIdx.x;
    const int n = nt * 16 + (l & 15);
    const int k0 = ks * 32 + (l >> 4) * 8;
    unsigned u[4];
    #pragma unroll
    for (int r = 0; r < 4; ++r)
        u[r] = bfpack(W[(k0 + 2*r) * HC + n], W[(k0 + 2*r + 1) * HC + n]);
    wf[bid * 64 + l] = make_uint4(u[0], u[1], u[2], u[3]);
}

// ---- K1: h = x @ W via MFMA (+ fused attention dots); h stored bf16 ----
__global__ __launch_bounds__(256) void k_gemm(
    const float* __restrict__ x, const uint4* __restrict__ wf,
    const float* __restrict__ atts, const float* __restrict__ attd,
    unsigned* __restrict__ hB, float2* __restrict__ asrc2, float2* __restrict__ adst2)
{
    __shared__ uint4 wl[2048];   // 32 KB: B-fragments for all (ks, nt)
    for (int i = threadIdx.x; i < 2048; i += 256) wl[i] = wf[i];
    __syncthreads();

    const int wv = threadIdx.x >> 6, lane = threadIdx.x & 63;
    const int g = lane >> 4, c15 = lane & 15;

    float As[8], Ad[8];
    #pragma unroll
    for (int nt = 0; nt < 8; ++nt) {
        As[nt] = atts[nt * 16 + c15];
        Ad[nt] = attd[nt * 16 + c15];
    }

    for (int t = blockIdx.x * 4 + wv; t < NTILE; t += gridDim.x * 4) {
        const int row0 = t * 16;
        // A-fragments: lane reads x[row0+c15][g*8 + ks*32 .. +7] (fp32->bf16)
        union { unsigned u[4]; short8 v; } af[4];
        const float* xr = x + (size_t)(row0 + c15) * HC + g * 8;
        #pragma unroll
        for (int ks = 0; ks < 4; ++ks) {
            float4 lo = *(const float4*)(xr + ks * 32);
            float4 hi = *(const float4*)(xr + ks * 32 + 4);
            af[ks].u[0] = bfpack(lo.x, lo.y);
            af[ks].u[1] = bfpack(lo.z, lo.w);
            af[ks].u[2] = bfpack(hi.x, hi.y);
            af[ks].u[3] = bfpack(hi.z, hi.w);
        }
        f32x4 acc[8];
        #pragma unroll
        for (int nt = 0; nt < 8; ++nt) acc[nt] = (f32x4)(0.f);
        #pragma unroll
        for (int nt = 0; nt < 8; ++nt) {
            #pragma unroll
            for (int ks = 0; ks < 4; ++ks) {
                short8 bfr = *(const short8*)&wl[(ks * 8 + nt) * 64 + lane];
                acc[nt] = __builtin_amdgcn_mfma_f32_16x16x32_bf16(
                    af[ks].v, bfr, acc[nt], 0, 0, 0);
            }
        }
        // epilogue: C/D layout col=lane&15, row=(lane>>4)*4+r  (m89-verified)
        #pragma unroll
        for (int r = 0; r < 4; ++r) {
            const int row = row0 + g * 4 + r;
            float ps = 0.f, pd = 0.f, qs = 0.f, qd = 0.f;
            #pragma unroll
            for (int nt = 0; nt < 4; ++nt) {
                float a = acc[nt][r], b = acc[nt + 4][r];
                hB[(size_t)row * 64 + nt * 16 + c15] = bfpack(a, b);
                ps += a * As[nt];     qs += a * Ad[nt];
                pd += b * As[nt + 4]; qd += b * Ad[nt + 4];
            }
            for (int off = 8; off; off >>= 1) {
                ps += __shfl_xor(ps, off); pd += __shfl_xor(pd, off);
                qs += __shfl_xor(qs, off); qd += __shfl_xor(qd, off);
            }
            if (c15 == 0) {
                asrc2[row] = make_float2(ps, pd);
                adst2[row] = make_float2(qs, qd);
            }
        }
    }
}

__device__ __forceinline__ void edge_sd(const int* __restrict__ ei, int t, int& s, int& d) {
    if (t < EE) { s = ei[t]; d = ei[EE + t]; }
    else        { s = t - EE; d = t - EE; }           // self-loops appended
}

// ---- CSR build ----
__global__ __launch_bounds__(256) void k_hist(const int* __restrict__ ei,
                                              int* __restrict__ hist)
{
    int t = blockIdx.x * 256 + threadIdx.x;
    if (t >= ET) return;
    int d = (t < EE) ? ei[EE + t] : (t - EE);
    atomicAdd(&hist[d], 1);
}

__global__ __launch_bounds__(256) void k_scan1(const int* __restrict__ hist,
                                               int* __restrict__ part)
{
    __shared__ int ls[256];
    int i = blockIdx.x * 256 + threadIdx.x;
    ls[threadIdx.x] = (i < NN) ? hist[i] : 0;
    __syncthreads();
    for (int off = 128; off; off >>= 1) {
        if (threadIdx.x < off) ls[threadIdx.x] += ls[threadIdx.x + off];
        __syncthreads();
    }
    if (!threadIdx.x) part[blockIdx.x] = ls[0];
}

__global__ __launch_bounds__(512) void k_scan2(int* __restrict__ part)
{
    __shared__ int ls[512];
    int tid = threadIdx.x;
    int v = (tid < NB) ? part[tid] : 0;
    ls[tid] = v;
    __syncthreads();
    for (int off = 1; off < 512; off <<= 1) {
        int t = (tid >= off) ? ls[tid - off] : 0;
        __syncthreads();
        ls[tid] += t;
        __syncthreads();
    }
    if (tid < NB) part[tid] = ls[tid] - v;   // exclusive block offsets
}

__global__ __launch_bounds__(256) void k_scan3(const int* __restrict__ hist,
                                               const int* __restrict__ part,
                                               int* __restrict__ row_ptr)
{
    __shared__ int ls[256];
    int i = blockIdx.x * 256 + threadIdx.x;
    int v = (i < NN) ? hist[i] : 0;
    ls[threadIdx.x] = v;
    __syncthreads();
    for (int off = 1; off < 256; off <<= 1) {
        int t = (threadIdx.x >= off) ? ls[threadIdx.x - off] : 0;
        __syncthreads();
        ls[threadIdx.x] += t;
        __syncthreads();
    }
    if (i < NN) row_ptr[i] = part[blockIdx.x] + ls[threadIdx.x] - v;  // exclusive
    if (i == 0) row_ptr[NN] = ET;
}

// bucket edges by dst; also compute p = exp(leaky_relu(logit)) in CSR order
__global__ __launch_bounds__(256) void k_bucket(
    const int* __restrict__ ei, const float* __restrict__ asrc,
    const float* __restrict__ adst, const int* __restrict__ row_ptr,
    int* __restrict__ cursor, int* __restrict__ csr_src, float2* __restrict__ pexp)
{
    int t = blockIdx.x * 256 + threadIdx.x;
    if (t >= ET) return;
    int s, d; edge_sd(ei, t, s, d);
    float2 av = *(const float2*)&asrc[s * 2];
    float2 dv = *(const float2*)&adst[d * 2];
    float e0 = av.x + dv.x; e0 = e0 > 0.f ? e0 : 0.2f * e0;
    float e1 = av.y + dv.y; e1 = e1 > 0.f ? e1 : 0.2f * e1;
    int pos = row_ptr[d] + atomicAdd(&cursor[d], 1);
    csr_src[pos] = s;
    pexp[pos] = make_float2(__expf(e0), __expf(e1));
}

// 8 independent gathers issued + drained in ONE asm block (sound: nothing can
// land between issue and drain). saddr form: 32-bit voffset + SGPR base.
__device__ __forceinline__ void gather8(const unsigned* base, const unsigned* off,
                                        unsigned* w) {
    asm volatile(
        "global_load_dword %0, %8,  %16\n\t"
        "global_load_dword %1, %9,  %16\n\t"
        "global_load_dword %2, %10, %16\n\t"
        "global_load_dword %3, %11, %16\n\t"
        "global_load_dword %4, %12, %16\n\t"
        "global_load_dword %5, %13, %16\n\t"
        "global_load_dword %6, %14, %16\n\t"
        "global_load_dword %7, %15, %16\n\t"
        "s_waitcnt vmcnt(0)"
        : "=&v"(w[0]), "=&v"(w[1]), "=&v"(w[2]), "=&v"(w[3]),
          "=&v"(w[4]), "=&v"(w[5]), "=&v"(w[6]), "=&v"(w[7])
        : "v"(off[0]), "v"(off[1]), "v"(off[2]), "v"(off[3]),
          "v"(off[4]), "v"(off[5]), "v"(off[6]), "v"(off[7]),
          "s"(base)
        : "memory");
}

// ---- K-agg: persistent blocks, BN partials written non-atomically ----
__global__ __launch_bounds__(256) void k_agg(
    const int* __restrict__ row_ptr, const int* __restrict__ csr_src,
    const float2* __restrict__ pexp, const unsigned* __restrict__ hB,
    const float* __restrict__ bias,
    float* __restrict__ out, float* __restrict__ bpart)
{
    __shared__ float lsum[HC], lsq[HC];
    __shared__ int    lidx[4][64];
    __shared__ float2 lp[4][64];
    const int tid = threadIdx.x;
    if (tid < HC) { lsum[tid] = 0.f; lsq[tid] = 0.f; }
    __syncthreads();

    const int wv = tid >> 6, lane = tid & 63;
    const float b0c = bias[lane], b1c = bias[64 + lane];

    for (int g = blockIdx.x; g < NGRP; g += AGG_BLOCKS) {
        const int node = g * 4 + wv;
        const int beg = row_ptr[node], end = row_ptr[node + 1];  // end > beg

        float s0 = 0.f, s1 = 0.f;
        float acc0 = 0.f, acc1 = 0.f;

        for (int base = beg; base < end; base += 64) {
            const int cnt = min(64, end - base);   // >= 1
            if (lane < cnt) {
                float2 pv = pexp[base + lane];
                lidx[wv][lane] = csr_src[base + lane];
                lp[wv][lane] = pv;
                s0 += pv.x; s1 += pv.y;
            }
            for (int j0 = 0; j0 < cnt; j0 += 8) {
                unsigned off[8], w[8];
                float pwx[8], pwy[8];
                #pragma unroll
                for (int u = 0; u < 8; ++u) {
                    int j  = j0 + u;
                    int jc = j < cnt ? j : cnt - 1;     // clamp (wave-uniform)
                    int s  = lidx[wv][jc];
                    float2 pv = lp[wv][jc];
                    pwx[u] = j < cnt ? pv.x : 0.f;      // zero pad weight
                    pwy[u] = j < cnt ? pv.y : 0.f;
                    off[u] = ((unsigned)s * 64u + (unsigned)lane) * 4u;
                }
                gather8(hB, off, w);
                #pragma unroll
                for (int u = 0; u < 8; ++u) {
                    acc0 = fmaf(pwx[u], __uint_as_float(w[u] << 16),         acc0);
                    acc1 = fmaf(pwy[u], __uint_as_float(w[u] & 0xffff0000u), acc1);
                }
            }
        }

        for (int off = 32; off; off >>= 1) {
            s0 += __shfl_xor(s0, off);
            s1 += __shfl_xor(s1, off);
        }

        float v0 = acc0 / s0 + b0c;  v0 = v0 > 0.f ? v0 : 0.f;
        float v1 = acc1 / s1 + b1c;  v1 = v1 > 0.f ? v1 : 0.f;
        out[(size_t)node * HC + lane]      = v0;
        out[(size_t)node * HC + 64 + lane] = v1;

        atomicAdd(&lsum[lane], v0);      atomicAdd(&lsq[lane], v0 * v0);
        atomicAdd(&lsum[64 + lane], v1); atomicAdd(&lsq[64 + lane], v1 * v1);
    }

    __syncthreads();
    // one coalesced non-atomic write of this block's 256 partials
    bpart[(size_t)blockIdx.x * 256 + tid] = tid < HC ? lsum[tid] : lsq[tid - HC];
}

// ---- reduce bpart[2048][256] -> p2[16][256] (atomic-free) ----
__global__ __launch_bounds__(256) void k_red(const float* __restrict__ bpart,
                                             float* __restrict__ p2)
{
    const int tid = threadIdx.x;
    float acc = 0.f;
    const int r0 = blockIdx.x * (AGG_BLOCKS / 16);
    #pragma unroll 4
    for (int r = 0; r < AGG_BLOCKS / 16; ++r)
        acc += bpart[(size_t)(r0 + r) * 256 + tid];
    p2[blockIdx.x * 256 + tid] = acc;
}

// ---- BN scale/shift from p2[16][256] ----
__global__ void k_bnparam(const float* __restrict__ p2,
                          const float* __restrict__ gamma, const float* __restrict__ beta,
                          float* __restrict__ scsh)
{
    int c = threadIdx.x;  // 128
    float sum = 0.f, sq = 0.f;
    #pragma unroll
    for (int i = 0; i < 16; ++i) {
        sum += p2[i * 256 + c];
        sq  += p2[i * 256 + c + 128];
    }
    float mean = sum * (1.f / NN);
    float var  = sq * (1.f / NN) - mean * mean;
    float sc   = gamma[c] * rsqrtf(var + 1e-5f);
    scsh[c]       = sc;
    scsh[128 + c] = beta[c] - mean * sc;
}

// ---- affine apply in place (float4) ----
__global__ __launch_bounds__(256) void k_apply(float* __restrict__ out,
                                               const float* __restrict__ scsh)
{
    size_t i = (size_t)blockIdx.x * 256 + threadIdx.x;
    if (i * 4 >= (size_t)NN * HC) return;
    float4 v = ((float4*)out)[i];
    int c = (int)((i * 4) & (HC - 1));
    v.x = v.x * scsh[c]     + scsh[128 + c];
    v.y = v.y * scsh[c + 1] + scsh[128 + c + 1];
    v.z = v.z * scsh[c + 2] + scsh[128 + c + 2];
    v.w = v.w * scsh[c + 3] + scsh[128 + c + 3];
    ((float4*)out)[i] = v;
}

extern "C" void kernel_launch(void* const* d_in, const int* in_sizes, int n_in,
                              void* d_out, int out_size, void* d_ws, size_t ws_size,
                              hipStream_t stream) {
    const float* x     = (const float*)d_in[0];
    const int*   ei    = (const int*)  d_in[1];
    const float* W     = (const float*)d_in[2];
    const float* atts  = (const float*)d_in[3];
    const float* attd  = (const float*)d_in[4];
    const float* bias  = (const float*)d_in[5];
    const float* gamma = (const float*)d_in[6];
    const float* beta  = (const float*)d_in[7];
    float* out = (float*)d_out;
    float* ws  = (float*)d_ws;

    // ws layout (float-sized slots), ~43.8 MB total
    unsigned* hB     = (unsigned*)ws;             //  6,400,000
    float*    asrc   = ws + 6400000;              //    200,000
    float*    adst   = ws + 6600000;              //    200,000
    int*      hist   = (int*)(ws + 6800000);      //    100,000  \  zeroed
    int*      cursor = (int*)(ws + 6900000);      //    100,000  /  region
    float*    scsh   = ws + 7000256;              //        256
    int*      row_ptr= (int*)(ws + 7000512);      //    100,001
    int*      part   = (int*)(ws + 7100513);      //        512
    int*      csr_src= (int*)(ws + 7101025);      //  1,100,000
    float2*   pexp   = (float2*)(ws + 8201026);   //  2,200,000 floats
    float*    bpart  = ws + 10401026;             //    524,288 (2048*256)
    float*    p2     = ws + 10925314;             //      4,096 (16*256)
    uint4*    wf     = (uint4*)(ws + 10929412);   //      8,192 floats (32KB, 16B-aligned)

    hipMemsetAsync(hist, 0, (size_t)200000 * sizeof(int), stream);

    k_wprep <<<32, 64, 0, stream>>>(W, wf);
    k_gemm  <<<782, 256, 0, stream>>>(x, wf, atts, attd, hB,
                                      (float2*)asrc, (float2*)adst);
    k_hist  <<<(ET + 255) / 256, 256, 0, stream>>>(ei, hist);
    k_scan1 <<<NB, 256, 0, stream>>>(hist, part);
    k_scan2 <<<1, 512, 0, stream>>>(part);
    k_scan3 <<<NB, 256, 0, stream>>>(hist, part, row_ptr);
    k_bucket<<<(ET + 255) / 256, 256, 0, stream>>>(ei, asrc, adst, row_ptr,
                                                   cursor, csr_src, pexp);
    k_agg   <<<AGG_BLOCKS, 256, 0, stream>>>(row_ptr, csr_src, pexp, hB, bias,
                                             out, bpart);
    k_red   <<<16, 256, 0, stream>>>(bpart, p2);
    k_bnparam<<<1, 128, 0, stream>>>(p2, gamma, beta, scsh);
    k_apply <<<(NN * HC / 4 + 255) / 256, 256, 0, stream>>>(out, scsh);
}